// Round 19
// baseline (488.032 us; speedup 1.0000x reference)
//
#include <hip/hip_runtime.h>
#include <cstdint>
#include <cstddef>

#define B_   4096
#define T_   128
#define IN_  768
#define H_   256
#define BM_  256          // batch rows per workgroup (two 128-row x tiles)
#define KC1  (IN_ / 32)   // 24 k-chunks, layer 1
#define KC2  (H_ / 32)    // 8  k-chunks, layer 2

typedef __bf16 bf16_t;
typedef bf16_t bf16x8 __attribute__((ext_vector_type(8)));
typedef bf16_t bf16x4 __attribute__((ext_vector_type(4)));
typedef float  floatx16 __attribute__((ext_vector_type(16)));

#define MFMA32(a, b, c) __builtin_amdgcn_mfma_f32_32x32x16_bf16((a), (b), (c), 0, 0, 0)

// Counted-vmcnt barriers (T3/T4): never drain vmcnt to 0 in steady-state loops.
// EVERY barrier carries lgkmcnt(0): drains this wave's ds_reads pre-barrier so a
// post-barrier global_load_lds restage can't WAR-race them (round-3 lesson).
#define WAITBAR(N) asm volatile("s_waitcnt vmcnt(" #N ") lgkmcnt(0)\n\ts_barrier" ::: "memory")
#define WAIT_LGK_BAR() asm volatile("s_waitcnt lgkmcnt(0)\n\ts_barrier" ::: "memory")

__device__ __forceinline__ void gl_lds16(const bf16_t* g, bf16_t* l) {
    __builtin_amdgcn_global_load_lds(
        (const __attribute__((address_space(1))) void*)g,
        (__attribute__((address_space(3))) void*)l, 16, 0, 0);
}

// ---------- prep bodies (merged into one dispatch) ----------
// W [t][K][H] fp32 -> A-frag tiles [t][kc][kq=4][h=256][8k] bf16
__device__ __forceinline__ void tile_w_body(const float* __restrict__ src,
                                            bf16_t* __restrict__ dst,
                                            int K, int KC, int blk) {
    const int t  = blk / KC;
    const int kc = blk - t * KC;
    const int kq = threadIdx.x >> 6;           // 0..3
    const int h4 = (threadIdx.x & 63) * 4;     // 0..252
    const float* s = src + ((size_t)t * K + kc * 32 + kq * 8) * H_ + h4;
    float r[8][4];
#pragma unroll
    for (int e = 0; e < 8; ++e) {
        float4 v = *(const float4*)(s + (size_t)e * H_);
        r[e][0] = v.x; r[e][1] = v.y; r[e][2] = v.z; r[e][3] = v.w;
    }
    bf16_t* d = dst + (((size_t)(t * KC + kc) * 4 + kq) * H_ + h4) * 8;
#pragma unroll
    for (int c = 0; c < 4; ++c) {
        bf16x8 v;
#pragma unroll
        for (int e = 0; e < 8; ++e) v[e] = (bf16_t)r[e][c];
        *(bf16x8*)(d + c * 8) = v;
    }
}

// x [B][IN] fp32 -> B-frag tiles [mblk=32][kc][kq=4][m=128][8k] bf16
__device__ __forceinline__ void tile_x_body(const float* __restrict__ src,
                                            bf16_t* __restrict__ dst, long long o) {
    int m = (int)(o & 127);
    long long q = o >> 7;
    int kq = (int)(q & 3);
    int q2 = (int)(q >> 2);
    int kc   = q2 % KC1;
    int mblk = q2 / KC1;
    const float* s = src + ((long long)mblk * 128 + m) * IN_ + kc * 32 + kq * 8;
    float4 a = *(const float4*)s;
    float4 b = *(const float4*)(s + 4);
    bf16x8 v;
    v[0] = (bf16_t)a.x; v[1] = (bf16_t)a.y; v[2] = (bf16_t)a.z; v[3] = (bf16_t)a.w;
    v[4] = (bf16_t)b.x; v[5] = (bf16_t)b.y; v[6] = (bf16_t)b.z; v[7] = (bf16_t)b.w;
    *(bf16x8*)(dst + o * 8) = v;
}

__global__ __launch_bounds__(256)
void prep_all(const float* __restrict__ x,  bf16_t* __restrict__ xt,
              const float* __restrict__ W1, bf16_t* __restrict__ w1t,
              const float* __restrict__ W2, bf16_t* __restrict__ w2t) {
    const int b = blockIdx.x;
    if (b < 1536) {
        long long o = (long long)b * 256 + threadIdx.x;   // < 393216 exactly
        tile_x_body(x, xt, o);
    } else if (b < 1536 + 3072) {
        tile_w_body(W1, w1t, IN_, KC1, b - 1536);
    } else {
        tile_w_body(W2, w2t, H_, KC2, b - 4608);
    }
}

// ---------- fused MLP: 512 threads, 256 rows, 1 WG/CU ----------
// BARRIER COUNT 43 -> 16 (R11 showed neither LDS nor VMEM bandwidth binds;
// the shared residual across all versions is per-barrier convergence+refill
// cost at 1 WG/CU).
//  * Layer 1: 2-chunk super-iterations. W ring-6 (3 pairs x 32KB in hbuf),
//    x register ring of 2 pairs, W staged at pair-distance 2. Block order
//    [x-loads(8), W-gl_lds(4)] -> exact WAITBAR(4) ledger. 12 barriers total,
//    256 MFMA per barrier.
//  * Layer 2: ZERO barriers. W2 A-frags global->registers (ring-2, compiler-
//    managed waits via register dataflow; same addressing as the proven LDS
//    comp2). h1 in hbuf is read-only during L2 -> waves fully desynchronized.
//  * Remaining barriers: 12 (L1) + 4 WAIT_LGK_BAR (ring->ep1, ep1->L2,
//    L2->ep2 WAR guard, ep2->L3).
// (R17 fix: SUPER takes x-register PREFIXES directly — single-level token
// paste; the previous two-level XU##A indirection pasted before expansion
// and produced undeclared identifiers.)
__global__ __launch_bounds__(512, 2)
void mtmlp_fused6(const bf16_t* __restrict__ xt, const bf16_t* __restrict__ w1t,
                  const float* __restrict__ b1, const bf16_t* __restrict__ w2t,
                  const float* __restrict__ b2, const float* __restrict__ W3,
                  const float* __restrict__ b3, float* __restrict__ out) {
    const int L    = blockIdx.x;          // 0..2047
    const int xcd  = L & 7;
    const int slot = L >> 3;              // 0..255
    const int t    = xcd * 16 + (slot >> 4);
    const int mblk = slot & 15;
    const int m0   = mblk * BM_;
    const int mb0  = mblk * 2;            // 128-row tile index

    const int tid  = threadIdx.x;
    const int lane = tid & 63;
    const int wid  = tid >> 6;            // 0..7
    const int wm   = wid >> 2;            // 0..1 : h half (128)
    const int wn   = wid & 3;             // 0..3 : m quarter (64)
    const int ln31 = lane & 31;
    const int hi   = lane >> 5;

    __shared__ __align__(16) bf16_t hbuf[BM_ * H_];   // 128 KB: W ring-6 (96K), then h1/h2
    __shared__ float w3s[H_];                          // 1 KB: W3 for layer 3

    floatx16 acc[4][2];
#pragma unroll
    for (int i = 0; i < 4; ++i)
#pragma unroll
        for (int j = 0; j < 2; ++j)
#pragma unroll
            for (int e = 0; e < 16; ++e) acc[i][j][e] = 0.0f;

    const bf16_t* w1base = w1t + (size_t)t * KC1 * 8192;
    const bf16_t* w2base = w2t + (size_t)t * KC2 * 8192;
    // per-wave x base: 128-row tile (mb0 + wn>>1), row base (wn&1)*64
    const bf16_t* xw = xt + (size_t)(mb0 + (wn >> 1)) * KC1 * 4096;
    // element offsets inside a 4096-elem x chunk: +S*2048 +J*256 added statically
    const int lbase = hi * 1024 + (wn & 1) * 512 + ln31 * 8;
    // element offsets inside an 8192-elem W chunk: +S*4096 +I*256 added statically
    const int abase = hi * 2048 + wm * 1024 + ln31 * 8;
    const int mm0 = wn * 64 + ln31;       // layer-2 B rows
    const int mm1 = mm0 + 32;

    // W ring-6: 3 pairs of 32 KB (2 chunks each)
    bf16_t* const P0 = hbuf;
    bf16_t* const P1 = hbuf + 16384;
    bf16_t* const P2 = hbuf + 32768;

    auto stageWpair = [&](bf16_t* dst, int kc) {           // 4 vmcnt ops: chunks kc, kc+1
        const bf16_t* ws = w1base + (size_t)kc * 8192;
        gl_lds16(ws + tid * 8,         dst + tid * 8);
        gl_lds16(ws + 4096 + tid * 8,  dst + 4096 + tid * 8);
        gl_lds16(ws + 8192 + tid * 8,  dst + 8192 + tid * 8);
        gl_lds16(ws + 12288 + tid * 8, dst + 12288 + tid * 8);
    };

// x B-fragments: 4 global 16B loads into named registers (static, rule #20).
#define LOADX(XV, kcc) do {                                          \
        const bf16_t* xp_ = xw + (size_t)(kcc) * 4096;               \
        XV##0 = *(const bf16x8*)(xp_ + lbase + 0 * 2048 + 0 * 256);  \
        XV##1 = *(const bf16x8*)(xp_ + lbase + 0 * 2048 + 1 * 256);  \
        XV##2 = *(const bf16x8*)(xp_ + lbase + 1 * 2048 + 0 * 256);  \
        XV##3 = *(const bf16x8*)(xp_ + lbase + 1 * 2048 + 1 * 256);  \
    } while (0)

// A from LDS chunk slot, B from registers. 8 ds_read_b128 + 16 MFMA per chunk.
#define COMP1(bp_, XV) do {                                          \
        const bf16_t* b_ = (bp_);                                    \
        bf16x8 A0_, A1_, A2_, A3_;                                   \
        A0_ = *(const bf16x8*)(b_ + abase + 0 * 4096 + 0 * 256);     \
        A1_ = *(const bf16x8*)(b_ + abase + 0 * 4096 + 1 * 256);     \
        A2_ = *(const bf16x8*)(b_ + abase + 0 * 4096 + 2 * 256);     \
        A3_ = *(const bf16x8*)(b_ + abase + 0 * 4096 + 3 * 256);     \
        acc[0][0] = MFMA32(A0_, XV##0, acc[0][0]);                   \
        acc[0][1] = MFMA32(A0_, XV##1, acc[0][1]);                   \
        acc[1][0] = MFMA32(A1_, XV##0, acc[1][0]);                   \
        acc[1][1] = MFMA32(A1_, XV##1, acc[1][1]);                   \
        acc[2][0] = MFMA32(A2_, XV##0, acc[2][0]);                   \
        acc[2][1] = MFMA32(A2_, XV##1, acc[2][1]);                   \
        acc[3][0] = MFMA32(A3_, XV##0, acc[3][0]);                   \
        acc[3][1] = MFMA32(A3_, XV##1, acc[3][1]);                   \
        A0_ = *(const bf16x8*)(b_ + abase + 1 * 4096 + 0 * 256);     \
        A1_ = *(const bf16x8*)(b_ + abase + 1 * 4096 + 1 * 256);     \
        A2_ = *(const bf16x8*)(b_ + abase + 1 * 4096 + 2 * 256);     \
        A3_ = *(const bf16x8*)(b_ + abase + 1 * 4096 + 3 * 256);     \
        acc[0][0] = MFMA32(A0_, XV##2, acc[0][0]);                   \
        acc[0][1] = MFMA32(A0_, XV##3, acc[0][1]);                   \
        acc[1][0] = MFMA32(A1_, XV##2, acc[1][0]);                   \
        acc[1][1] = MFMA32(A1_, XV##3, acc[1][1]);                   \
        acc[2][0] = MFMA32(A2_, XV##2, acc[2][0]);                   \
        acc[2][1] = MFMA32(A2_, XV##3, acc[2][1]);                   \
        acc[3][0] = MFMA32(A3_, XV##2, acc[3][0]);                   \
        acc[3][1] = MFMA32(A3_, XV##3, acc[3][1]);                   \
    } while (0)

// One L1 super-iteration p (chunks c=2p, c+1): barrier (W pair p + x pair p
// ready, W pair p+1 stays in flight), issue x pair p+1 (8 ops) then W pair p+2
// (4 ops), compute pair p. Ledger at each WAITBAR: outstanding =
// [W(p)(4), x(p)(8), W(p+1)(4)] -> drain oldest 12 -> vmcnt(4).
// XUa/XUb = x prefixes to USE; XNa/XNb = x prefixes to LOAD NEXT.
#define SUPER(CB, WB, XUa, XUb, XNa, XNb, c) do {                    \
        WAITBAR(4);                                                  \
        LOADX(XNa, (c) + 2); LOADX(XNb, (c) + 3);                    \
        stageWpair(WB, (c) + 4);                                     \
        COMP1(CB, XUa); COMP1((CB) + 8192, XUb);                     \
    } while (0)

    bf16x8 xPA0, xPA1, xPA2, xPA3, xPB0, xPB1, xPB2, xPB3;   // x pair P
    bf16x8 xQA0, xQA1, xQA2, xQA3, xQB0, xQB1, xQB2, xQB3;   // x pair Q

    // ---------------- layer 1 ----------------
    // Prologue: x pair0 (8 ops), W pairs 0,1 (8 ops). 16 in flight.
    LOADX(xPA, 0); LOADX(xPB, 1);
    stageWpair(P0, 0);
    stageWpair(P1, 2);

    // p = 0..9 (chunks 0..19); slot period 3, x parity 2.
    SUPER(P0, P2, xPA, xPB, xQA, xQB, 0);    // p=0: use P, load Q
    SUPER(P1, P0, xQA, xQB, xPA, xPB, 2);    // p=1
    SUPER(P2, P1, xPA, xPB, xQA, xQB, 4);    // p=2
    SUPER(P0, P2, xQA, xQB, xPA, xPB, 6);    // p=3
    SUPER(P1, P0, xPA, xPB, xQA, xQB, 8);    // p=4
    SUPER(P2, P1, xQA, xQB, xPA, xPB, 10);   // p=5
    SUPER(P0, P2, xPA, xPB, xQA, xQB, 12);   // p=6
    SUPER(P1, P0, xQA, xQB, xPA, xPB, 14);   // p=7
    SUPER(P2, P1, xPA, xPB, xQA, xQB, 16);   // p=8
    SUPER(P0, P2, xQA, xQB, xPA, xPB, 18);   // p=9: stages chunks 22,23 into P2
    // p=10 (chunks 20,21): no W stage left; load x pair 11.
    WAITBAR(4);
    LOADX(xQA, 22); LOADX(xQB, 23);
    COMP1(P1, xPA); COMP1(P1 + 8192, xPB);
    // p=11 (chunks 22,23): drain everything (tail).
    WAITBAR(0);
    COMP1(P2, xQA); COMP1(P2 + 8192, xQB);
    WAIT_LGK_BAR();   // ring reads drained before epilogue overwrites hbuf

    // epilogue 1: bias + relu -> hbuf [blk=h/8][m=256][8h]
#pragma unroll
    for (int i = 0; i < 4; ++i) {
#pragma unroll
        for (int g = 0; g < 4; ++g) {
            const int h0 = wm * 128 + i * 32 + g * 8 + 4 * hi;
            float4 bias = *(const float4*)(b1 + t * H_ + h0);
            const int blk = h0 >> 3;
#pragma unroll
            for (int j = 0; j < 2; ++j) {
                const int mm = wn * 64 + j * 32 + ln31;
                bf16x4 o;
                o[0] = (bf16_t)fmaxf(acc[i][j][4 * g + 0] + bias.x, 0.0f);
                o[1] = (bf16_t)fmaxf(acc[i][j][4 * g + 1] + bias.y, 0.0f);
                o[2] = (bf16_t)fmaxf(acc[i][j][4 * g + 2] + bias.z, 0.0f);
                o[3] = (bf16_t)fmaxf(acc[i][j][4 * g + 3] + bias.w, 0.0f);
                *(bf16x4*)(hbuf + (size_t)(blk * BM_ + mm) * 8 + 4 * hi) = o;
            }
        }
    }

#pragma unroll
    for (int i = 0; i < 4; ++i)
#pragma unroll
        for (int j = 0; j < 2; ++j)
#pragma unroll
            for (int e = 0; e < 16; ++e) acc[i][j][e] = 0.0f;

    WAIT_LGK_BAR();   // h1 ds_writes drained + barrier: h1 visible to all waves

    // ---------------- layer 2: h2^T = W2^T · h1^T — ZERO barriers ----------------
    // W2 A-frags global->registers, ring-2; B-frags from hbuf (read-only h1).
    // Compiler inserts vmcnt/lgkmcnt waits via register dataflow.
#define LOADW2(WV, kcc) do {                                         \
        const bf16_t* wp_ = w2base + (size_t)(kcc) * 8192;           \
        WV##0 = *(const bf16x8*)(wp_ + abase + 0 * 4096 + 0 * 256);  \
        WV##1 = *(const bf16x8*)(wp_ + abase + 0 * 4096 + 1 * 256);  \
        WV##2 = *(const bf16x8*)(wp_ + abase + 0 * 4096 + 2 * 256);  \
        WV##3 = *(const bf16x8*)(wp_ + abase + 0 * 4096 + 3 * 256);  \
        WV##4 = *(const bf16x8*)(wp_ + abase + 1 * 4096 + 0 * 256);  \
        WV##5 = *(const bf16x8*)(wp_ + abase + 1 * 4096 + 1 * 256);  \
        WV##6 = *(const bf16x8*)(wp_ + abase + 1 * 4096 + 2 * 256);  \
        WV##7 = *(const bf16x8*)(wp_ + abase + 1 * 4096 + 3 * 256);  \
    } while (0)

#define COMP2R(WV, kcc) do {                                         \
        bf16x8 B0_, B1_;                                             \
        const int blkA_ = (kcc) * 4 + hi;                            \
        B0_ = *(const bf16x8*)(hbuf + (size_t)(blkA_ * BM_ + mm0) * 8); \
        B1_ = *(const bf16x8*)(hbuf + (size_t)(blkA_ * BM_ + mm1) * 8); \
        acc[0][0] = MFMA32(WV##0, B0_, acc[0][0]);                   \
        acc[0][1] = MFMA32(WV##0, B1_, acc[0][1]);                   \
        acc[1][0] = MFMA32(WV##1, B0_, acc[1][0]);                   \
        acc[1][1] = MFMA32(WV##1, B1_, acc[1][1]);                   \
        acc[2][0] = MFMA32(WV##2, B0_, acc[2][0]);                   \
        acc[2][1] = MFMA32(WV##2, B1_, acc[2][1]);                   \
        acc[3][0] = MFMA32(WV##3, B0_, acc[3][0]);                   \
        acc[3][1] = MFMA32(WV##3, B1_, acc[3][1]);                   \
        const int blkB_ = (kcc) * 4 + 2 + hi;                        \
        B0_ = *(const bf16x8*)(hbuf + (size_t)(blkB_ * BM_ + mm0) * 8); \
        B1_ = *(const bf16x8*)(hbuf + (size_t)(blkB_ * BM_ + mm1) * 8); \
        acc[0][0] = MFMA32(WV##4, B0_, acc[0][0]);                   \
        acc[0][1] = MFMA32(WV##4, B1_, acc[0][1]);                   \
        acc[1][0] = MFMA32(WV##5, B0_, acc[1][0]);                   \
        acc[1][1] = MFMA32(WV##5, B1_, acc[1][1]);                   \
        acc[2][0] = MFMA32(WV##6, B0_, acc[2][0]);                   \
        acc[2][1] = MFMA32(WV##6, B1_, acc[2][1]);                   \
        acc[3][0] = MFMA32(WV##7, B0_, acc[3][0]);                   \
        acc[3][1] = MFMA32(WV##7, B1_, acc[3][1]);                   \
    } while (0)

    {
        bf16x8 wa0, wa1, wa2, wa3, wa4, wa5, wa6, wa7;
        bf16x8 wb0, wb1, wb2, wb3, wb4, wb5, wb6, wb7;
        LOADW2(wa, 0); LOADW2(wb, 1);
        COMP2R(wa, 0); LOADW2(wa, 2);
        COMP2R(wb, 1); LOADW2(wb, 3);
        COMP2R(wa, 2); LOADW2(wa, 4);
        COMP2R(wb, 3); LOADW2(wb, 5);
        COMP2R(wa, 4); LOADW2(wa, 6);
        COMP2R(wb, 5); LOADW2(wb, 7);
        COMP2R(wa, 6);
        COMP2R(wb, 7);
    }

    WAIT_LGK_BAR();   // all waves done reading h1 before epilogue-2 overwrites it

    // epilogue 2: bias + relu -> h2 (hbuf, same layout); stage W3 into w3s
    if (tid < H_) w3s[tid] = W3[t * H_ + tid];
#pragma unroll
    for (int i = 0; i < 4; ++i) {
#pragma unroll
        for (int g = 0; g < 4; ++g) {
            const int h0 = wm * 128 + i * 32 + g * 8 + 4 * hi;
            float4 bias = *(const float4*)(b2 + t * H_ + h0);
            const int blk = h0 >> 3;
#pragma unroll
            for (int j = 0; j < 2; ++j) {
                const int mm = wn * 64 + j * 32 + ln31;
                bf16x4 o;
                o[0] = (bf16_t)fmaxf(acc[i][j][4 * g + 0] + bias.x, 0.0f);
                o[1] = (bf16_t)fmaxf(acc[i][j][4 * g + 1] + bias.y, 0.0f);
                o[2] = (bf16_t)fmaxf(acc[i][j][4 * g + 2] + bias.z, 0.0f);
                o[3] = (bf16_t)fmaxf(acc[i][j][4 * g + 3] + bias.w, 0.0f);
                *(bf16x4*)(hbuf + (size_t)(blk * BM_ + mm) * 8 + 4 * hi) = o;
            }
        }
    }
    WAIT_LGK_BAR();   // own ds_writes drained, then barrier: h2 + w3s visible

    // ---------------- layer 3: out[m,t] = h2[m,:]·W3[t,:] + b3[t] ----------------
    {
        const int m = tid >> 1, seg = tid & 1;   // 2 threads/row, 128 h each
        float sum = 0.0f;
#pragma unroll
        for (int b = 0; b < 16; ++b) {
            const int blk = seg * 16 + b;
            const bf16x8 v = *(const bf16x8*)(hbuf + (size_t)(blk * BM_ + m) * 8);
            const float* w = w3s + blk * 8;
#pragma unroll
            for (int e = 0; e < 8; ++e) sum += (float)v[e] * w[e];
        }
        sum += __shfl_xor(sum, 1);
        if (seg == 0) out[(size_t)(m0 + m) * T_ + t] = sum + b3[t];
    }
#undef LOADX
#undef COMP1
#undef SUPER
#undef LOADW2
#undef COMP2R
}

extern "C" void kernel_launch(void* const* d_in, const int* in_sizes, int n_in,
                              void* d_out, int out_size, void* d_ws, size_t ws_size,
                              hipStream_t stream) {
    const float* x  = (const float*)d_in[0];
    const float* W1 = (const float*)d_in[1];
    const float* b1 = (const float*)d_in[2];
    const float* W2 = (const float*)d_in[3];
    const float* b2 = (const float*)d_in[4];
    const float* W3 = (const float*)d_in[5];
    const float* b3 = (const float*)d_in[6];
    float* out = (float*)d_out;

    const size_t nx  = (size_t)B_ * IN_;        // 3,145,728
    const size_t nw1 = (size_t)T_ * IN_ * H_;   // 25,165,824

    bf16_t* xt  = (bf16_t*)d_ws;
    bf16_t* w1t = xt + nx;
    bf16_t* w2t = w1t + nw1;

    prep_all<<<dim3(5632), 256, 0, stream>>>(x, xt, W1, w1t, W2, w2t);
    mtmlp_fused6<<<dim3(2048), 512, 0, stream>>>(xt, w1t, b1, w2t, b2, W3, b3, out);
}

// Round 20
// 484.040 us; speedup vs baseline: 1.0082x; 1.0082x over previous
//
#include <hip/hip_runtime.h>
#include <cstdint>
#include <cstddef>

#define B_   4096
#define T_   128
#define IN_  768
#define H_   256
#define BM_  128          // batch rows per workgroup (one 128-row x tile)
#define KC1  (IN_ / 32)   // 24 k-chunks, layer 1
#define KC2  (H_ / 32)    // 8  k-chunks, layer 2

typedef __bf16 bf16_t;
typedef bf16_t bf16x8 __attribute__((ext_vector_type(8)));
typedef bf16_t bf16x4 __attribute__((ext_vector_type(4)));
typedef float  floatx16 __attribute__((ext_vector_type(16)));

#define MFMA32(a, b, c) __builtin_amdgcn_mfma_f32_32x32x16_bf16((a), (b), (c), 0, 0, 0)

// Counted-vmcnt barriers; every barrier carries lgkmcnt(0) (round-3 WAR lesson).
#define WAITBAR(N) asm volatile("s_waitcnt vmcnt(" #N ") lgkmcnt(0)\n\ts_barrier" ::: "memory")
#define WAIT_LGK_BAR() asm volatile("s_waitcnt lgkmcnt(0)\n\ts_barrier" ::: "memory")

__device__ __forceinline__ void gl_lds16(const bf16_t* g, bf16_t* l) {
    __builtin_amdgcn_global_load_lds(
        (const __attribute__((address_space(1))) void*)g,
        (__attribute__((address_space(3))) void*)l, 16, 0, 0);
}

// ---------- prep bodies (merged into one dispatch; verified) ----------
__device__ __forceinline__ void tile_w_body(const float* __restrict__ src,
                                            bf16_t* __restrict__ dst,
                                            int K, int KC, int blk) {
    const int t  = blk / KC;
    const int kc = blk - t * KC;
    const int kq = threadIdx.x >> 6;
    const int h4 = (threadIdx.x & 63) * 4;
    const float* s = src + ((size_t)t * K + kc * 32 + kq * 8) * H_ + h4;
    float r[8][4];
#pragma unroll
    for (int e = 0; e < 8; ++e) {
        float4 v = *(const float4*)(s + (size_t)e * H_);
        r[e][0] = v.x; r[e][1] = v.y; r[e][2] = v.z; r[e][3] = v.w;
    }
    bf16_t* d = dst + (((size_t)(t * KC + kc) * 4 + kq) * H_ + h4) * 8;
#pragma unroll
    for (int c = 0; c < 4; ++c) {
        bf16x8 v;
#pragma unroll
        for (int e = 0; e < 8; ++e) v[e] = (bf16_t)r[e][c];
        *(bf16x8*)(d + c * 8) = v;
    }
}

__device__ __forceinline__ void tile_x_body(const float* __restrict__ src,
                                            bf16_t* __restrict__ dst, long long o) {
    int m = (int)(o & 127);
    long long q = o >> 7;
    int kq = (int)(q & 3);
    int q2 = (int)(q >> 2);
    int kc   = q2 % KC1;
    int mblk = q2 / KC1;
    const float* s = src + ((long long)mblk * 128 + m) * IN_ + kc * 32 + kq * 8;
    float4 a = *(const float4*)s;
    float4 b = *(const float4*)(s + 4);
    bf16x8 v;
    v[0] = (bf16_t)a.x; v[1] = (bf16_t)a.y; v[2] = (bf16_t)a.z; v[3] = (bf16_t)a.w;
    v[4] = (bf16_t)b.x; v[5] = (bf16_t)b.y; v[6] = (bf16_t)b.z; v[7] = (bf16_t)b.w;
    *(bf16x8*)(dst + o * 8) = v;
}

__global__ __launch_bounds__(256)
void prep_all(const float* __restrict__ x,  bf16_t* __restrict__ xt,
              const float* __restrict__ W1, bf16_t* __restrict__ w1t,
              const float* __restrict__ W2, bf16_t* __restrict__ w2t) {
    const int b = blockIdx.x;
    if (b < 1536) {
        long long o = (long long)b * 256 + threadIdx.x;
        tile_x_body(x, xt, o);
    } else if (b < 1536 + 3072) {
        tile_w_body(W1, w1t, IN_, KC1, b - 1536);
    } else {
        tile_w_body(W2, w2t, H_, KC2, b - 4608);
    }
}

// ---------- fused MLP: 512 threads, BM=128, LDS 65.5 KB -> 2 WGs/CU ----------
// OCCUPANCY is the round-20 lever: every prior version ran 8 waves/CU (2/SIMD,
// 23%) and was latency-bound (all pipes <30%). This version: 8 waves own 32
// rows x 128 h each (acc[4], 64 VGPR); h1 = 64 KB; W ring-4 of 16KB chunks
// fills hbuf during L1; x in registers (2 bf16x8/chunk, ring-2); L2 uses the
// R19-verified register-W2 path (halved, zero barriers) which 4 waves/SIMD can
// latency-hide; W3 in a 1 KB LDS array. Total 65.5 KB -> 2 WGs x 8 waves = 16
// waves/CU (4/SIMD). L1 keeps fused5's single-WAITBAR-per-chunk counted-vmcnt
// discipline; ledger re-derived by queue simulation (steady WAITBAR(4)).
__global__ __launch_bounds__(512, 4)
void mtmlp_fused7(const bf16_t* __restrict__ xt, const bf16_t* __restrict__ w1t,
                  const float* __restrict__ b1, const bf16_t* __restrict__ w2t,
                  const float* __restrict__ b2, const float* __restrict__ W3,
                  const float* __restrict__ b3, float* __restrict__ out) {
    // XCD swizzle: XCD k owns tasks [16k,16k+16) (32 mblks each).
    const int L    = blockIdx.x;          // 0..4095
    const int xcd  = L & 7;
    const int slot = L >> 3;              // 0..511
    const int t    = xcd * 16 + (slot >> 5);
    const int mblk = slot & 31;
    const int m0   = mblk * BM_;

    const int tid  = threadIdx.x;
    const int lane = tid & 63;
    const int wid  = tid >> 6;            // 0..7
    const int wm   = wid >> 2;            // 0..1 : h half (128)
    const int wn   = wid & 3;             // 0..3 : 32-row group
    const int ln31 = lane & 31;
    const int hi   = lane >> 5;

    __shared__ __align__(16) bf16_t hbuf[BM_ * H_];   // 64 KB: W ring-4, then h1/h2
    __shared__ float w3s[H_];                          // 1 KB

    floatx16 acc[4];
#pragma unroll
    for (int i = 0; i < 4; ++i)
#pragma unroll
        for (int e = 0; e < 16; ++e) acc[i][e] = 0.0f;

    const bf16_t* w1base = w1t + (size_t)t * KC1 * 8192;
    const bf16_t* w2base = w2t + (size_t)t * KC2 * 8192;
    const bf16_t* xw = xt + (size_t)mblk * KC1 * 4096;
    const int mmx  = wn * 32 + ln31;                   // this wave's m rows
    const int xoff = hi * 1024 + mmx * 8;              // x: (kq=hi)*128*8 + m*8
    const int aoff = hi * 2048 + wm * 1024 + ln31 * 8; // W: kq-half + h-col

    bf16_t* const sl0 = hbuf;
    bf16_t* const sl1 = hbuf + 8192;
    bf16_t* const sl2 = hbuf + 16384;
    bf16_t* const sl3 = hbuf + 24576;

    auto stageW = [&](bf16_t* dst, int kc) {           // 2 vmcnt ops: 16KB chunk
        const bf16_t* ws = w1base + (size_t)kc * 8192;
        gl_lds16(ws + tid * 8,        dst + tid * 8);
        gl_lds16(ws + 4096 + tid * 8, dst + 4096 + tid * 8);
    };

// x B-fragments: 2 global 16B loads into named registers.
#define LOADX(XV, kcc) do {                                          \
        const bf16_t* xp_ = xw + (size_t)(kcc) * 4096;               \
        XV##0 = *(const bf16x8*)(xp_ + xoff);                        \
        XV##1 = *(const bf16x8*)(xp_ + xoff + 2048);                 \
    } while (0)

// A from LDS slot (4 i-blocks x 2 k-slices), B from registers. 8 MFMA/chunk.
#define COMP1(bp_, XV) do {                                          \
        const bf16_t* b_ = (bp_);                                    \
        bf16x8 A0_, A1_, A2_, A3_;                                   \
        A0_ = *(const bf16x8*)(b_ + aoff + 0 * 256);                 \
        A1_ = *(const bf16x8*)(b_ + aoff + 1 * 256);                 \
        A2_ = *(const bf16x8*)(b_ + aoff + 2 * 256);                 \
        A3_ = *(const bf16x8*)(b_ + aoff + 3 * 256);                 \
        acc[0] = MFMA32(A0_, XV##0, acc[0]);                         \
        acc[1] = MFMA32(A1_, XV##0, acc[1]);                         \
        acc[2] = MFMA32(A2_, XV##0, acc[2]);                         \
        acc[3] = MFMA32(A3_, XV##0, acc[3]);                         \
        A0_ = *(const bf16x8*)(b_ + aoff + 4096 + 0 * 256);          \
        A1_ = *(const bf16x8*)(b_ + aoff + 4096 + 1 * 256);          \
        A2_ = *(const bf16x8*)(b_ + aoff + 4096 + 2 * 256);         \
        A3_ = *(const bf16x8*)(b_ + aoff + 4096 + 3 * 256);          \
        acc[0] = MFMA32(A0_, XV##1, acc[0]);                         \
        acc[1] = MFMA32(A1_, XV##1, acc[1]);                         \
        acc[2] = MFMA32(A2_, XV##1, acc[2]);                         \
        acc[3] = MFMA32(A3_, XV##1, acc[3]);                         \
    } while (0)

    bf16x8 xA0, xA1, xB0, xB1;   // x ring-2

    // ---------------- layer 1 ----------------
    // Prologue: x chunks 0,1 (4 ops) THEN W chunks 0..2 (6 ops); queue
    // [x0 x1 W0 W1 W2]. Per-iteration order: WAITBAR; stageW; COMP1; LOADX
    // (x reload AFTER its consumer). Ledger from queue simulation.
    LOADX(xA, 0); LOADX(xB, 1);
    stageW(sl0, 0); stageW(sl1, 1); stageW(sl2, 2);

    WAITBAR(4); stageW(sl3, 3);  COMP1(sl0, xA); LOADX(xA, 2);    // kc=0
    WAITBAR(6); stageW(sl0, 4);  COMP1(sl1, xB); LOADX(xB, 3);    // kc=1
    WAITBAR(4); stageW(sl1, 5);  COMP1(sl2, xA); LOADX(xA, 4);    // kc=2
    WAITBAR(4); stageW(sl2, 6);  COMP1(sl3, xB); LOADX(xB, 5);    // kc=3
    WAITBAR(4); stageW(sl3, 7);  COMP1(sl0, xA); LOADX(xA, 6);    // kc=4
    WAITBAR(4); stageW(sl0, 8);  COMP1(sl1, xB); LOADX(xB, 7);    // kc=5
    WAITBAR(4); stageW(sl1, 9);  COMP1(sl2, xA); LOADX(xA, 8);    // kc=6
    WAITBAR(4); stageW(sl2, 10); COMP1(sl3, xB); LOADX(xB, 9);    // kc=7
    WAITBAR(4); stageW(sl3, 11); COMP1(sl0, xA); LOADX(xA, 10);   // kc=8
    WAITBAR(4); stageW(sl0, 12); COMP1(sl1, xB); LOADX(xB, 11);   // kc=9
    WAITBAR(4); stageW(sl1, 13); COMP1(sl2, xA); LOADX(xA, 12);   // kc=10
    WAITBAR(4); stageW(sl2, 14); COMP1(sl3, xB); LOADX(xB, 13);   // kc=11
    WAITBAR(4); stageW(sl3, 15); COMP1(sl0, xA); LOADX(xA, 14);   // kc=12
    WAITBAR(4); stageW(sl0, 16); COMP1(sl1, xB); LOADX(xB, 15);   // kc=13
    WAITBAR(4); stageW(sl1, 17); COMP1(sl2, xA); LOADX(xA, 16);   // kc=14
    WAITBAR(4); stageW(sl2, 18); COMP1(sl3, xB); LOADX(xB, 17);   // kc=15
    WAITBAR(4); stageW(sl3, 19); COMP1(sl0, xA); LOADX(xA, 18);   // kc=16
    WAITBAR(4); stageW(sl0, 20); COMP1(sl1, xB); LOADX(xB, 19);   // kc=17
    WAITBAR(4); stageW(sl1, 21); COMP1(sl2, xA); LOADX(xA, 20);   // kc=18
    WAITBAR(4); stageW(sl2, 22); COMP1(sl3, xB); LOADX(xB, 21);   // kc=19
    WAITBAR(4); stageW(sl3, 23); COMP1(sl0, xA); LOADX(xA, 22);   // kc=20
    WAITBAR(4);                  COMP1(sl1, xB); LOADX(xB, 23);   // kc=21
    WAITBAR(2);                  COMP1(sl2, xA);                  // kc=22
    WAITBAR(0);                  COMP1(sl3, xB);                  // kc=23
    WAIT_LGK_BAR();   // ring reads drained before epilogue overwrites hbuf

    // epilogue 1: bias + relu -> hbuf [blk=h/8][m=128][8h]
#pragma unroll
    for (int i = 0; i < 4; ++i) {
#pragma unroll
        for (int g = 0; g < 4; ++g) {
            const int h0 = wm * 128 + i * 32 + g * 8 + 4 * hi;
            float4 bias = *(const float4*)(b1 + t * H_ + h0);
            const int blk = h0 >> 3;
            bf16x4 o;
            o[0] = (bf16_t)fmaxf(acc[i][4 * g + 0] + bias.x, 0.0f);
            o[1] = (bf16_t)fmaxf(acc[i][4 * g + 1] + bias.y, 0.0f);
            o[2] = (bf16_t)fmaxf(acc[i][4 * g + 2] + bias.z, 0.0f);
            o[3] = (bf16_t)fmaxf(acc[i][4 * g + 3] + bias.w, 0.0f);
            *(bf16x4*)(hbuf + (size_t)(blk * BM_ + mmx) * 8 + 4 * hi) = o;
        }
    }

#pragma unroll
    for (int i = 0; i < 4; ++i)
#pragma unroll
        for (int e = 0; e < 16; ++e) acc[i][e] = 0.0f;

    WAIT_LGK_BAR();   // h1 ds_writes drained + barrier: h1 visible to all waves

    // ---------------- layer 2: h2^T = W2^T · h1^T — register W2, zero barriers
    // k-slice ks=0..15 (16 h1 elems each). A = W2^T frags direct from global
    // (R19-verified addressing, halved); B = h1 from hbuf (read-only).
#define LOADW2H(WV, ks) do {                                         \
        const bf16_t* wp_ = w2base + ((ks) >> 1) * 8192              \
                            + ((ks) & 1) * 4096 + aoff;              \
        WV##0 = *(const bf16x8*)(wp_ + 0 * 256);                     \
        WV##1 = *(const bf16x8*)(wp_ + 1 * 256);                     \
        WV##2 = *(const bf16x8*)(wp_ + 2 * 256);                     \
        WV##3 = *(const bf16x8*)(wp_ + 3 * 256);                     \
    } while (0)

#define COMP2H(WV, ks) do {                                          \
        const bf16x8 Bf_ = *(const bf16x8*)(hbuf +                   \
            (size_t)(((ks) * 2 + hi) * BM_ + mmx) * 8);              \
        acc[0] = MFMA32(WV##0, Bf_, acc[0]);                         \
        acc[1] = MFMA32(WV##1, Bf_, acc[1]);                         \
        acc[2] = MFMA32(WV##2, Bf_, acc[2]);                         \
        acc[3] = MFMA32(WV##3, Bf_, acc[3]);                         \
    } while (0)

    {
        bf16x8 wa0, wa1, wa2, wa3;
        bf16x8 wb0, wb1, wb2, wb3;
        LOADW2H(wa, 0);  LOADW2H(wb, 1);
        COMP2H(wa, 0);   LOADW2H(wa, 2);
        COMP2H(wb, 1);   LOADW2H(wb, 3);
        COMP2H(wa, 2);   LOADW2H(wa, 4);
        COMP2H(wb, 3);   LOADW2H(wb, 5);
        COMP2H(wa, 4);   LOADW2H(wa, 6);
        COMP2H(wb, 5);   LOADW2H(wb, 7);
        COMP2H(wa, 6);   LOADW2H(wa, 8);
        COMP2H(wb, 7);   LOADW2H(wb, 9);
        COMP2H(wa, 8);   LOADW2H(wa, 10);
        COMP2H(wb, 9);   LOADW2H(wb, 11);
        COMP2H(wa, 10);  LOADW2H(wa, 12);
        COMP2H(wb, 11);  LOADW2H(wb, 13);
        COMP2H(wa, 12);  LOADW2H(wa, 14);
        COMP2H(wb, 13);  LOADW2H(wb, 15);
        COMP2H(wa, 14);
        COMP2H(wb, 15);
    }

    WAIT_LGK_BAR();   // all waves done reading h1 before epilogue-2 overwrites it

    // epilogue 2: bias + relu -> h2 (hbuf, same layout); stage W3 into w3s
    if (tid < H_) w3s[tid] = W3[t * H_ + tid];
#pragma unroll
    for (int i = 0; i < 4; ++i) {
#pragma unroll
        for (int g = 0; g < 4; ++g) {
            const int h0 = wm * 128 + i * 32 + g * 8 + 4 * hi;
            float4 bias = *(const float4*)(b2 + t * H_ + h0);
            const int blk = h0 >> 3;
            bf16x4 o;
            o[0] = (bf16_t)fmaxf(acc[i][4 * g + 0] + bias.x, 0.0f);
            o[1] = (bf16_t)fmaxf(acc[i][4 * g + 1] + bias.y, 0.0f);
            o[2] = (bf16_t)fmaxf(acc[i][4 * g + 2] + bias.z, 0.0f);
            o[3] = (bf16_t)fmaxf(acc[i][4 * g + 3] + bias.w, 0.0f);
            *(bf16x4*)(hbuf + (size_t)(blk * BM_ + mmx) * 8 + 4 * hi) = o;
        }
    }
    WAIT_LGK_BAR();   // own ds_writes drained, then barrier: h2 + w3s visible

    // ---------------- layer 3: out[m,t] = h2[m,:]·W3[t,:] + b3[t] ----------------
    {
        const int m = tid >> 2, seg = tid & 3;   // 4 threads/row, 64 h each
        float sum = 0.0f;
#pragma unroll
        for (int b = 0; b < 8; ++b) {
            const int blk = seg * 8 + b;
            const bf16x8 v = *(const bf16x8*)(hbuf + (size_t)(blk * BM_ + m) * 8);
            const float* w = w3s + blk * 8;
#pragma unroll
            for (int e = 0; e < 8; ++e) sum += (float)v[e] * w[e];
        }
        sum += __shfl_xor(sum, 1);
        sum += __shfl_xor(sum, 2);
        if (seg == 0) out[(size_t)(m0 + m) * T_ + t] = sum + b3[t];
    }
#undef LOADX
#undef COMP1
#undef LOADW2H
#undef COMP2H
}

extern "C" void kernel_launch(void* const* d_in, const int* in_sizes, int n_in,
                              void* d_out, int out_size, void* d_ws, size_t ws_size,
                              hipStream_t stream) {
    const float* x  = (const float*)d_in[0];
    const float* W1 = (const float*)d_in[1];
    const float* b1 = (const float*)d_in[2];
    const float* W2 = (const float*)d_in[3];
    const float* b2 = (const float*)d_in[4];
    const float* W3 = (const float*)d_in[5];
    const float* b3 = (const float*)d_in[6];
    float* out = (float*)d_out;

    const size_t nx  = (size_t)B_ * IN_;        // 3,145,728
    const size_t nw1 = (size_t)T_ * IN_ * H_;   // 25,165,824

    bf16_t* xt  = (bf16_t*)d_ws;
    bf16_t* w1t = xt + nx;
    bf16_t* w2t = w1t + nw1;

    prep_all<<<dim3(5632), 256, 0, stream>>>(x, xt, W1, w1t, W2, w2t);
    mtmlp_fused7<<<dim3(4096), 512, 0, stream>>>(xt, w1t, b1, w2t, b2, W3, b3, out);
}